// Round 1
// baseline (116.679 us; speedup 1.0000x reference)
//
#include <hip/hip_runtime.h>

// Fold2D forward, channels_last, L=16, x:(8,512,512,32) f32.
// out(b,h,w,c) = y + [16<=w<32]*y(h,31-w),  y(h,w) = x + [16<=h<32]*x(31-h,w)
// Pure one-pass streaming kernel; float4 over the 32 contiguous channels.

__device__ __forceinline__ float4 add4(float4 a, float4 b) {
    return make_float4(a.x + b.x, a.y + b.y, a.z + b.z, a.w + b.w);
}

__global__ void __launch_bounds__(256) fold2d_kernel(const float4* __restrict__ x,
                                                     float4* __restrict__ out,
                                                     int total4) {
    const int stride = gridDim.x * blockDim.x;
    for (int idx = blockIdx.x * blockDim.x + threadIdx.x; idx < total4; idx += stride) {
        // idx = ((b*512 + h)*512 + w)*8 + c4
        const int w  = (idx >> 3) & 511;
        const int h  = (idx >> 12) & 511;

        float4 v = x[idx];
        const bool hf = ((unsigned)(h - 16)) < 16u;   // 16 <= h < 32
        const bool wf = ((unsigned)(w - 16)) < 16u;   // 16 <= w < 32

        // replacing h with 31-h shifts flat idx by (31-2h)*4096
        const int idxh = idx + ((31 - 2 * h) << 12);
        if (hf) v = add4(v, x[idxh]);
        if (wf) {
            const int dW = (31 - 2 * w) << 3;         // replace w with 31-w
            float4 u = x[idx + dW];
            if (hf) u = add4(u, x[idxh + dW]);
            v = add4(v, u);
        }
        out[idx] = v;
    }
}

extern "C" void kernel_launch(void* const* d_in, const int* in_sizes, int n_in,
                              void* d_out, int out_size, void* d_ws, size_t ws_size,
                              hipStream_t stream) {
    const float4* x  = (const float4*)d_in[0];
    float4* out      = (float4*)d_out;
    const int total4 = out_size / 4;   // 16,777,216 float4s

    const int block = 256;
    const int grid  = 2048;            // 8 blocks/CU, grid-stride covers the rest
    fold2d_kernel<<<grid, block, 0, stream>>>(x, out, total4);
}

// Round 2
// 82.704 us; speedup vs baseline: 1.4108x; 1.4108x over previous
//
#include <hip/hip_runtime.h>

// Fold2D forward, channels_last, L=16, x:(8,512,512,32) f32.
// out(b,h,w,c) = y + [16<=w<32]*y(h,31-w),  y(h,w) = x + [16<=h<32]*x(31-h,w)
//
// Layout: row (b,h) = 512 px * 32 ch = 4096 float4s. One block = quarter-row
// (1024 f4, 4 per thread). h-fold is block-uniform; w-fold (w in [16,32) ->
// f4 idx [128,256) of the row) lives entirely in quarter q==0, threads
// t>=128, chunk j==0 -- wave-uniform. All loads batch before one wait.

typedef float vfloat4 __attribute__((ext_vector_type(4)));

__device__ __forceinline__ vfloat4 ntload(const vfloat4* p) {
    return __builtin_nontemporal_load(p);
}

__global__ void __launch_bounds__(256) fold2d_row(const vfloat4* __restrict__ x,
                                                  vfloat4* __restrict__ out) {
    const int blk = blockIdx.x;           // 16384 blocks
    const int row = blk >> 2;             // b*512 + h   (4096 rows)
    const int q   = blk & 3;              // quarter of the row
    const int h   = row & 511;
    const int t   = threadIdx.x;

    const int rbase = row << 12;          // f4 index of row start
    const int o0    = (q << 10) + t;      // first of this thread's 4 chunks

    const bool hf = ((unsigned)(h - 16)) < 16u;          // 16 <= h < 32
    const int  mrow = (31 - 2 * h) << 12;                // f4 delta to mirrored row

    float4 v[4];
#pragma unroll
    for (int j = 0; j < 4; ++j)
        v[j] = *(const float4*)&x[rbase + o0 + (j << 8)];

    if (hf) {                                            // block-uniform branch
        float4 u[4];
#pragma unroll
        for (int j = 0; j < 4; ++j)
            u[j] = *(const float4*)&x[rbase + mrow + o0 + (j << 8)];
#pragma unroll
        for (int j = 0; j < 4; ++j) {
            v[j].x += u[j].x; v[j].y += u[j].y; v[j].z += u[j].z; v[j].w += u[j].w;
        }
    }

    if (q == 0 && t >= 128) {                            // wave-uniform (waves 2,3)
        // chunk j==0: in-row f4 index = t in [128,256), pixel w = t>>3 in [16,32)
        const int wm = (31 - 2 * (t >> 3)) << 3;         // f4 delta to mirrored w
        float4 u = *(const float4*)&x[rbase + t + wm];
        if (hf) {
            float4 u2 = *(const float4*)&x[rbase + mrow + t + wm];
            u.x += u2.x; u.y += u2.y; u.z += u2.z; u.w += u2.w;
        }
        v[0].x += u.x; v[0].y += u.y; v[0].z += u.z; v[0].w += u.w;
    }

#pragma unroll
    for (int j = 0; j < 4; ++j)
        __builtin_nontemporal_store(*(vfloat4*)&v[j], &out[rbase + o0 + (j << 8)]);
}

extern "C" void kernel_launch(void* const* d_in, const int* in_sizes, int n_in,
                              void* d_out, int out_size, void* d_ws, size_t ws_size,
                              hipStream_t stream) {
    const vfloat4* x = (const vfloat4*)d_in[0];
    vfloat4* out     = (vfloat4*)d_out;
    // 8*512 rows * 4 quarter-row blocks = 16384 blocks, 256 threads each.
    fold2d_row<<<16384, 256, 0, stream>>>(x, out);
}

// Round 3
// 82.700 us; speedup vs baseline: 1.4109x; 1.0000x over previous
//
#include <hip/hip_runtime.h>

// Fold2D forward, channels_last, L=16, x:(8,512,512,32) f32.
// out(b,h,w,c) = y + [16<=w<32]*y(h,31-w),  y(h,w) = x + [16<=h<32]*x(31-h,w)
//
// Row (b,h) = 512 px * 32 ch = 4096 float4s. One block = HALF-row (2048 f4,
// 8 per thread -> 8 outstanding 1KiB loads per wave before the single wait).
// h-fold is block-uniform; w-fold (f4 idx [128,256) of the row) lives in
// half q==0, threads t>=128, chunk j==0 -- wave-uniform.

typedef float vfloat4 __attribute__((ext_vector_type(4)));

__global__ void __launch_bounds__(256) fold2d_row(const vfloat4* __restrict__ x,
                                                  vfloat4* __restrict__ out) {
    const int blk = blockIdx.x;           // 8192 blocks
    const int row = blk >> 1;             // b*512 + h   (4096 rows)
    const int q   = blk & 1;              // half of the row
    const int h   = row & 511;
    const int t   = threadIdx.x;

    const int rbase = row << 12;          // f4 index of row start
    const int o0    = (q << 11) + t;      // first of this thread's 8 chunks

    const bool hf = ((unsigned)(h - 16)) < 16u;          // 16 <= h < 32
    const int  mrow = (31 - 2 * h) << 12;                // f4 delta to mirrored row

    float4 v[8];
#pragma unroll
    for (int j = 0; j < 8; ++j)
        v[j] = *(const float4*)&x[rbase + o0 + (j << 8)];

    if (hf) {                                            // block-uniform branch
        float4 u[8];
#pragma unroll
        for (int j = 0; j < 8; ++j)
            u[j] = *(const float4*)&x[rbase + mrow + o0 + (j << 8)];
#pragma unroll
        for (int j = 0; j < 8; ++j) {
            v[j].x += u[j].x; v[j].y += u[j].y; v[j].z += u[j].z; v[j].w += u[j].w;
        }
    }

    if (q == 0 && t >= 128) {                            // wave-uniform (waves 2,3)
        // chunk j==0: in-row f4 index = t in [128,256), pixel w = t>>3 in [16,32)
        const int wm = (31 - 2 * (t >> 3)) << 3;         // f4 delta to mirrored w
        float4 u = *(const float4*)&x[rbase + t + wm];
        if (hf) {
            float4 u2 = *(const float4*)&x[rbase + mrow + t + wm];
            u.x += u2.x; u.y += u2.y; u.z += u2.z; u.w += u2.w;
        }
        v[0].x += u.x; v[0].y += u.y; v[0].z += u.z; v[0].w += u.w;
    }

#pragma unroll
    for (int j = 0; j < 8; ++j)
        __builtin_nontemporal_store(*(vfloat4*)&v[j], &out[rbase + o0 + (j << 8)]);
}

extern "C" void kernel_launch(void* const* d_in, const int* in_sizes, int n_in,
                              void* d_out, int out_size, void* d_ws, size_t ws_size,
                              hipStream_t stream) {
    const vfloat4* x = (const vfloat4*)d_in[0];
    vfloat4* out     = (vfloat4*)d_out;
    // 8*512 rows * 2 half-row blocks = 8192 blocks, 256 threads each.
    fold2d_row<<<8192, 256, 0, stream>>>(x, out);
}